// Round 1
// baseline (1668.028 us; speedup 1.0000x reference)
//
#include <hip/hip_runtime.h>

#define C 128          // channels
#define THREADS_GEMM 512

// ---------------- graph structure build ----------------

__global__ void deg_kernel(const int* __restrict__ ei, int* __restrict__ deg, int E) {
    int e = blockIdx.x * blockDim.x + threadIdx.x;
    if (e < E) atomicAdd(&deg[ei[E + e]], 1);   // dst = ei[E+e]
}

// single block, 1024 threads: exclusive scan of deg -> offs[N+1], copy to fill
__global__ void scan_kernel(const int* __restrict__ deg, int* __restrict__ offs,
                            int* __restrict__ fill, int n) {
    __shared__ int part[1024];
    const int t = threadIdx.x;
    const int chunk = (n + 1023) >> 10;
    const int b = t * chunk;
    const int e = min(b + chunk, n);
    int s = 0;
    for (int i = b; i < e; i++) s += deg[i];
    part[t] = s;
    __syncthreads();
    for (int off = 1; off < 1024; off <<= 1) {
        int add = (t >= off) ? part[t - off] : 0;
        __syncthreads();
        part[t] += add;
        __syncthreads();
    }
    int run = (t > 0) ? part[t - 1] : 0;
    for (int i = b; i < e; i++) { offs[i] = run; fill[i] = run; run += deg[i]; }
    if (e == n) offs[n] = part[1023];
}

__global__ void prep_kernel(const int* __restrict__ deg, float* __restrict__ dinv,
                            float* __restrict__ cinv, int n) {
    int i = blockIdx.x * blockDim.x + threadIdx.x;
    if (i < n) {
        int d = deg[i];
        dinv[i] = rsqrtf((float)(d + 1));        // GCN: self-loop counted
        cinv[i] = 1.0f / (float)max(d, 1);       // SAGE mean divisor
    }
}

__global__ void csr_fill(const int* __restrict__ ei, int* __restrict__ fill,
                         int* __restrict__ csr, int E) {
    int e = blockIdx.x * blockDim.x + threadIdx.x;
    if (e < E) {
        int d = ei[E + e];
        int p = atomicAdd(&fill[d], 1);
        csr[p] = ei[e];                          // src
    }
}

// ---------------- GEMMs ----------------

// h = x @ W   (no bias, no relu). 512 thr: cg = (t&31)*4 ch, rs = t>>5 row slot,
// 2 rows/thread, 32 rows per iteration, 64 rows per block.
__global__ __launch_bounds__(THREADS_GEMM) void gemm_single(
        const float* __restrict__ x, const float* __restrict__ W,
        float* __restrict__ h) {
    __shared__ float Ws[128 * 128];   // 64 KB, Ws[k*128+c]
    __shared__ float xs[32][128];     // 16 KB
    const int t = threadIdx.x;
    for (int i = t; i < 128 * 32; i += THREADS_GEMM)      // float4 units
        ((float4*)Ws)[i] = ((const float4*)W)[i];
    const int cg = (t & 31) * 4;
    const int rs = t >> 5;            // 0..15
    const int r0 = blockIdx.x * 64;
    __syncthreads();
    for (int iter = 0; iter < 2; iter++) {
        const int rbase = r0 + iter * 32;
        for (int i = t; i < 32 * 32; i += THREADS_GEMM)   // 32 rows x 32 f4
            ((float4*)xs)[i] = ((const float4*)(x + (size_t)rbase * C))[i];
        __syncthreads();
        float4 a0 = {0, 0, 0, 0}, a1 = {0, 0, 0, 0};
        const float* xr0 = xs[rs];
        const float* xr1 = xs[rs + 16];
#pragma unroll 8
        for (int k = 0; k < 128; k++) {
            float4 w = *(const float4*)(Ws + k * 128 + cg);
            float v0 = xr0[k], v1 = xr1[k];
            a0.x += v0 * w.x; a0.y += v0 * w.y; a0.z += v0 * w.z; a0.w += v0 * w.w;
            a1.x += v1 * w.x; a1.y += v1 * w.y; a1.z += v1 * w.z; a1.w += v1 * w.w;
        }
        *(float4*)(h + (size_t)(rbase + rs) * C + cg) = a0;
        *(float4*)(h + (size_t)(rbase + rs + 16) * C + cg) = a1;
        __syncthreads();
    }
}

// out = relu(m @ Wl + bl + x @ Wr), channel-split in halves of 64.
// 512 thr: cg = (t&15)*4, rs = t>>4 (0..31), 2 rows/thread, 64 rows/iter, 128/block.
__global__ __launch_bounds__(THREADS_GEMM) void gemm_fused(
        const float* __restrict__ m, const float* __restrict__ x,
        const float* __restrict__ Wl, const float* __restrict__ bl,
        const float* __restrict__ Wr, float* __restrict__ out) {
    __shared__ float Wls[128 * 64];   // 32 KB, [k*64+c]
    __shared__ float Wrs[128 * 64];   // 32 KB
    __shared__ float ms[64][132];     // padded: row stride 132 -> bank spread
    __shared__ float xsm[64][132];
    const int t = threadIdx.x;
    const int ch0 = blockIdx.y * 64;
    for (int i = t; i < 128 * 16; i += THREADS_GEMM) {    // f4 units: 128 k x 16
        int k = i >> 4, c4 = i & 15;
        ((float4*)Wls)[i] = *(const float4*)(Wl + k * 128 + ch0 + c4 * 4);
        ((float4*)Wrs)[i] = *(const float4*)(Wr + k * 128 + ch0 + c4 * 4);
    }
    const int cg = (t & 15) * 4;
    const int rs = t >> 4;            // 0..31
    const int r0 = blockIdx.x * 128;
    const float4 b4 = *(const float4*)(bl + ch0 + cg);
    __syncthreads();
    for (int iter = 0; iter < 2; iter++) {
        const int rbase = r0 + iter * 64;
        for (int i = t; i < 64 * 32; i += THREADS_GEMM) { // 64 rows x 32 f4
            int r = i >> 5, c4 = i & 31;
            float4 mv = ((const float4*)(m + (size_t)rbase * C))[i];
            float4 xv = ((const float4*)(x + (size_t)rbase * C))[i];
            *(float4*)(&ms[r][c4 * 4]) = mv;
            *(float4*)(&xsm[r][c4 * 4]) = xv;
        }
        __syncthreads();
        float4 a0 = {0, 0, 0, 0}, a1 = {0, 0, 0, 0};
        const float* mr0 = ms[rs];  const float* mr1 = ms[rs + 32];
        const float* xr0 = xsm[rs]; const float* xr1 = xsm[rs + 32];
#pragma unroll 4
        for (int k = 0; k < 128; k++) {
            float4 wl = *(const float4*)(Wls + k * 64 + cg);
            float4 wr = *(const float4*)(Wrs + k * 64 + cg);
            float m0 = mr0[k], m1 = mr1[k], x0 = xr0[k], x1 = xr1[k];
            a0.x += m0 * wl.x + x0 * wr.x; a0.y += m0 * wl.y + x0 * wr.y;
            a0.z += m0 * wl.z + x0 * wr.z; a0.w += m0 * wl.w + x0 * wr.w;
            a1.x += m1 * wl.x + x1 * wr.x; a1.y += m1 * wl.y + x1 * wr.y;
            a1.z += m1 * wl.z + x1 * wr.z; a1.w += m1 * wl.w + x1 * wr.w;
        }
        a0.x = fmaxf(a0.x + b4.x, 0.f); a0.y = fmaxf(a0.y + b4.y, 0.f);
        a0.z = fmaxf(a0.z + b4.z, 0.f); a0.w = fmaxf(a0.w + b4.w, 0.f);
        a1.x = fmaxf(a1.x + b4.x, 0.f); a1.y = fmaxf(a1.y + b4.y, 0.f);
        a1.z = fmaxf(a1.z + b4.z, 0.f); a1.w = fmaxf(a1.w + b4.w, 0.f);
        *(float4*)(out + (size_t)(rbase + rs) * C + ch0 + cg) = a0;
        *(float4*)(out + (size_t)(rbase + rs + 32) * C + ch0 + cg) = a1;
        __syncthreads();
    }
}

// ---------------- aggregations (gather via CSR) ----------------

// out[i] = relu( dinv[i]*sum_{s in N(i)} h[s]*dinv[s] + h[i]*dinv[i]^2 + b )
__global__ __launch_bounds__(128) void gcn_agg(
        const float* __restrict__ h, const int* __restrict__ csr,
        const int* __restrict__ offs, const float* __restrict__ dinv,
        const float* __restrict__ bg, float* __restrict__ out) {
    const int i = blockIdx.x;
    const int c = threadIdx.x;
    const int b = offs[i], e = offs[i + 1];
    float acc = 0.f;
    for (int p = b; p < e; p++) {
        int s = csr[p];
        acc += h[(size_t)s * C + c] * dinv[s];
    }
    const float di = dinv[i];
    float v = acc * di + h[(size_t)i * C + c] * di * di + bg[c];
    out[(size_t)i * C + c] = fmaxf(v, 0.f);
}

// mean[i] = (sum_{s in N(i)} x[s]) * cinv[i]
__global__ __launch_bounds__(128) void sage_agg(
        const float* __restrict__ x, const int* __restrict__ csr,
        const int* __restrict__ offs, const float* __restrict__ cinv,
        float* __restrict__ mean) {
    const int i = blockIdx.x;
    const int c = threadIdx.x;
    const int b = offs[i], e = offs[i + 1];
    float acc = 0.f;
    for (int p = b; p < e; p++)
        acc += x[(size_t)csr[p] * C + c];
    mean[(size_t)i * C + c] = acc * cinv[i];
}

// ---------------- host ----------------

extern "C" void kernel_launch(void* const* d_in, const int* in_sizes, int n_in,
                              void* d_out, int out_size, void* d_ws, size_t ws_size,
                              hipStream_t stream) {
    const float* x   = (const float*)d_in[0];
    const float* W_g = (const float*)d_in[1];
    const float* b_g = (const float*)d_in[2];
    const float* W_l = (const float*)d_in[3];
    const float* b_l = (const float*)d_in[4];
    const float* W_r = (const float*)d_in[5];
    const int*   ei  = (const int*)d_in[6];

    const int N = in_sizes[0] / C;       // 102400
    const int E = in_sizes[6] / 2;       // 1638400

    // workspace carve (needs ~61.1 MB)
    char* ws = (char*)d_ws;
    float* hbuf = (float*)ws;                               // N*C f32 (h / mean)
    int*   csr  = (int*)(ws + (size_t)N * C * 4);           // E ints
    int*   deg  = csr + E;                                  // N
    int*   fill = deg + N;                                  // N
    int*   offs = fill + N;                                 // N+1 (+pad)
    float* dinv = (float*)(offs + N + 4);                   // N
    float* cinv = dinv + N;                                 // N

    float* out0 = (float*)d_out;                            // layer outputs, N*C each
    const size_t NC = (size_t)N * C;

    hipMemsetAsync(deg, 0, (size_t)N * 4, stream);
    deg_kernel<<<(E + 255) / 256, 256, 0, stream>>>(ei, deg, E);
    scan_kernel<<<1, 1024, 0, stream>>>(deg, offs, fill, N);
    prep_kernel<<<(N + 255) / 256, 256, 0, stream>>>(deg, dinv, cinv, N);
    csr_fill<<<(E + 255) / 256, 256, 0, stream>>>(ei, fill, csr, E);

    // ---- GCN layer -> out slot 0
    gemm_single<<<N / 64, THREADS_GEMM, 0, stream>>>(x, W_g, hbuf);
    gcn_agg<<<N, 128, 0, stream>>>(hbuf, csr, offs, dinv, b_g, out0);

    // ---- 3 SAGE layers -> out slots 1..3
    for (int l = 0; l < 3; l++) {
        const float* xin = out0 + (size_t)l * NC;
        float* yout      = out0 + (size_t)(l + 1) * NC;
        sage_agg<<<N, 128, 0, stream>>>(xin, csr, offs, cinv, hbuf);
        gemm_fused<<<dim3(N / 128, 2), THREADS_GEMM, 0, stream>>>(
            hbuf, xin, W_l + (size_t)l * C * C, b_l + (size_t)l * C,
            W_r + (size_t)l * C * C, yout);
    }
}

// Round 2
// 1226.687 us; speedup vs baseline: 1.3598x; 1.3598x over previous
//
#include <hip/hip_runtime.h>

#define C 128          // channels
#define THREADS_GEMM 512

// ---------------- graph structure build ----------------

__global__ void deg_kernel(const int* __restrict__ ei, int* __restrict__ deg, int E) {
    int e = blockIdx.x * blockDim.x + threadIdx.x;
    if (e < E) atomicAdd(&deg[ei[E + e]], 1);   // dst = ei[E+e]
}

// phase A: 256 thr x 4 elems = 1024 elems/block -> bsum[block]
__global__ __launch_bounds__(256) void scan_partial(const int* __restrict__ deg,
                                                    int* __restrict__ bsum, int n) {
    __shared__ int red[4];
    const int base = blockIdx.x * 1024 + threadIdx.x * 4;
    int s = 0;
#pragma unroll
    for (int j = 0; j < 4; j++) { int i = base + j; if (i < n) s += deg[i]; }
    for (int off = 32; off > 0; off >>= 1) s += __shfl_down(s, off);
    if ((threadIdx.x & 63) == 0) red[threadIdx.x >> 6] = s;
    __syncthreads();
    if (threadIdx.x == 0) bsum[blockIdx.x] = red[0] + red[1] + red[2] + red[3];
}

// phase B: single block, scan the (<=128) block sums -> exclusive bases; offs[n]=E
__global__ __launch_bounds__(128) void scan_mid(int* __restrict__ bsum,
                                                int* __restrict__ offs, int nb, int n) {
    __shared__ int sh[128];
    const int t = threadIdx.x;
    const int v = (t < nb) ? bsum[t] : 0;
    sh[t] = v;
    __syncthreads();
    for (int off = 1; off < 128; off <<= 1) {
        int add = (t >= off) ? sh[t - off] : 0;
        __syncthreads();
        sh[t] += add;
        __syncthreads();
    }
    if (t < nb) bsum[t] = sh[t] - v;      // exclusive base for block t
    if (t == nb - 1) offs[n] = sh[t];     // total edge count
}

// phase C: per-block LDS scan of 1024 degs + base add; also dinv/cinv (prep fold)
__global__ __launch_bounds__(1024) void scan_final(const int* __restrict__ deg,
        const int* __restrict__ bsum, int* __restrict__ offs, int* __restrict__ fill,
        float* __restrict__ dinv, float* __restrict__ cinv, int n) {
    __shared__ int sh[1024];
    const int t = threadIdx.x;
    const int gi = blockIdx.x * 1024 + t;
    const int d = (gi < n) ? deg[gi] : 0;
    sh[t] = d;
    __syncthreads();
    for (int off = 1; off < 1024; off <<= 1) {
        int add = (t >= off) ? sh[t - off] : 0;
        __syncthreads();
        sh[t] += add;
        __syncthreads();
    }
    if (gi < n) {
        const int excl = bsum[blockIdx.x] + sh[t] - d;
        offs[gi] = excl;
        fill[gi] = excl;
        dinv[gi] = rsqrtf((float)(d + 1));       // GCN: self-loop counted
        cinv[gi] = 1.0f / (float)max(d, 1);      // SAGE mean divisor
    }
}

__global__ void csr_fill(const int* __restrict__ ei, int* __restrict__ fill,
                         int* __restrict__ csr, int E) {
    int e = blockIdx.x * blockDim.x + threadIdx.x;
    if (e < E) {
        int d = ei[E + e];
        int p = atomicAdd(&fill[d], 1);
        csr[p] = ei[e];                          // src
    }
}

// ---------------- GEMMs ----------------

// hs = (x @ W) * dinv[row]   (pre-scaled for GCN agg)
__global__ __launch_bounds__(THREADS_GEMM) void gemm_single(
        const float* __restrict__ x, const float* __restrict__ W,
        const float* __restrict__ dinv, float* __restrict__ h) {
    __shared__ float Ws[128 * 128];   // 64 KB, Ws[k*128+c]
    __shared__ float xs[32][128];     // 16 KB
    const int t = threadIdx.x;
    for (int i = t; i < 128 * 32; i += THREADS_GEMM)      // float4 units
        ((float4*)Ws)[i] = ((const float4*)W)[i];
    const int cg = (t & 31) * 4;
    const int rs = t >> 5;            // 0..15
    const int r0 = blockIdx.x * 64;
    __syncthreads();
    for (int iter = 0; iter < 2; iter++) {
        const int rbase = r0 + iter * 32;
        for (int i = t; i < 32 * 32; i += THREADS_GEMM)   // 32 rows x 32 f4
            ((float4*)xs)[i] = ((const float4*)(x + (size_t)rbase * C))[i];
        __syncthreads();
        float4 a0 = {0, 0, 0, 0}, a1 = {0, 0, 0, 0};
        const float* xr0 = xs[rs];
        const float* xr1 = xs[rs + 16];
#pragma unroll 8
        for (int k = 0; k < 128; k++) {
            float4 w = *(const float4*)(Ws + k * 128 + cg);
            float v0 = xr0[k], v1 = xr1[k];
            a0.x += v0 * w.x; a0.y += v0 * w.y; a0.z += v0 * w.z; a0.w += v0 * w.w;
            a1.x += v1 * w.x; a1.y += v1 * w.y; a1.z += v1 * w.z; a1.w += v1 * w.w;
        }
        const float d0 = dinv[rbase + rs], d1 = dinv[rbase + rs + 16];
        a0.x *= d0; a0.y *= d0; a0.z *= d0; a0.w *= d0;
        a1.x *= d1; a1.y *= d1; a1.z *= d1; a1.w *= d1;
        *(float4*)(h + (size_t)(rbase + rs) * C + cg) = a0;
        *(float4*)(h + (size_t)(rbase + rs + 16) * C + cg) = a1;
        __syncthreads();
    }
}

// out = relu(m @ Wl + bl + x @ Wr), channel-split in halves of 64.
__global__ __launch_bounds__(THREADS_GEMM) void gemm_fused(
        const float* __restrict__ m, const float* __restrict__ x,
        const float* __restrict__ Wl, const float* __restrict__ bl,
        const float* __restrict__ Wr, float* __restrict__ out) {
    __shared__ float Wls[128 * 64];   // 32 KB, [k*64+c]
    __shared__ float Wrs[128 * 64];   // 32 KB
    __shared__ float ms[64][132];     // padded: row stride 132 -> bank spread
    __shared__ float xsm[64][132];
    const int t = threadIdx.x;
    const int ch0 = blockIdx.y * 64;
    for (int i = t; i < 128 * 16; i += THREADS_GEMM) {    // f4 units: 128 k x 16
        int k = i >> 4, c4 = i & 15;
        ((float4*)Wls)[i] = *(const float4*)(Wl + k * 128 + ch0 + c4 * 4);
        ((float4*)Wrs)[i] = *(const float4*)(Wr + k * 128 + ch0 + c4 * 4);
    }
    const int cg = (t & 15) * 4;
    const int rs = t >> 4;            // 0..31
    const int r0 = blockIdx.x * 128;
    const float4 b4 = *(const float4*)(bl + ch0 + cg);
    __syncthreads();
    for (int iter = 0; iter < 2; iter++) {
        const int rbase = r0 + iter * 64;
        for (int i = t; i < 64 * 32; i += THREADS_GEMM) { // 64 rows x 32 f4
            int r = i >> 5, c4 = i & 31;
            float4 mv = ((const float4*)(m + (size_t)rbase * C))[i];
            float4 xv = ((const float4*)(x + (size_t)rbase * C))[i];
            *(float4*)(&ms[r][c4 * 4]) = mv;
            *(float4*)(&xsm[r][c4 * 4]) = xv;
        }
        __syncthreads();
        float4 a0 = {0, 0, 0, 0}, a1 = {0, 0, 0, 0};
        const float* mr0 = ms[rs];  const float* mr1 = ms[rs + 32];
        const float* xr0 = xsm[rs]; const float* xr1 = xsm[rs + 32];
#pragma unroll 4
        for (int k = 0; k < 128; k++) {
            float4 wl = *(const float4*)(Wls + k * 64 + cg);
            float4 wr = *(const float4*)(Wrs + k * 64 + cg);
            float m0 = mr0[k], m1 = mr1[k], x0 = xr0[k], x1 = xr1[k];
            a0.x += m0 * wl.x + x0 * wr.x; a0.y += m0 * wl.y + x0 * wr.y;
            a0.z += m0 * wl.z + x0 * wr.z; a0.w += m0 * wl.w + x0 * wr.w;
            a1.x += m1 * wl.x + x1 * wr.x; a1.y += m1 * wl.y + x1 * wr.y;
            a1.z += m1 * wl.z + x1 * wr.z; a1.w += m1 * wl.w + x1 * wr.w;
        }
        a0.x = fmaxf(a0.x + b4.x, 0.f); a0.y = fmaxf(a0.y + b4.y, 0.f);
        a0.z = fmaxf(a0.z + b4.z, 0.f); a0.w = fmaxf(a0.w + b4.w, 0.f);
        a1.x = fmaxf(a1.x + b4.x, 0.f); a1.y = fmaxf(a1.y + b4.y, 0.f);
        a1.z = fmaxf(a1.z + b4.z, 0.f); a1.w = fmaxf(a1.w + b4.w, 0.f);
        *(float4*)(out + (size_t)(rbase + rs) * C + ch0 + cg) = a0;
        *(float4*)(out + (size_t)(rbase + rs + 32) * C + ch0 + cg) = a1;
        __syncthreads();
    }
}

// ---------------- unified aggregation (gather via CSR) ----------------
// wave-per-node, float2 per lane (64 lanes x 8B = 512B/row), CSR prefetched
// into registers (one coalesced load per 64 neighbors) + __shfl broadcast.
// SELF:     add tbl[i] to the sum before scaling (GCN self-loop, pre-scaled h)
// BIASRELU: out = relu(sum*scale + bias); else out = sum*scale
template<int SELF, int BIASRELU>
__global__ __launch_bounds__(256) void agg_kernel(
        const float* __restrict__ tbl, const int* __restrict__ csr,
        const int* __restrict__ offs, const float* __restrict__ scale,
        const float* __restrict__ bias, float* __restrict__ out, int n) {
    const int lane = threadIdx.x & 63;
    const int i = (blockIdx.x << 2) + (threadIdx.x >> 6);
    if (i >= n) return;
    const int b = offs[i], e = offs[i + 1];
    const int c2 = lane * 2;
    float ax = 0.f, ay = 0.f;
    for (int base = b; base < e; base += 64) {
        const int cnt = min(64, e - base);
        int idx = (base + lane < e) ? csr[base + lane] : 0;
        int p = 0;
        for (; p + 4 <= cnt; p += 4) {
            int s0 = __shfl(idx, p);
            int s1 = __shfl(idx, p + 1);
            int s2 = __shfl(idx, p + 2);
            int s3 = __shfl(idx, p + 3);
            float2 v0 = *(const float2*)(tbl + (size_t)s0 * C + c2);
            float2 v1 = *(const float2*)(tbl + (size_t)s1 * C + c2);
            float2 v2 = *(const float2*)(tbl + (size_t)s2 * C + c2);
            float2 v3 = *(const float2*)(tbl + (size_t)s3 * C + c2);
            ax += v0.x + v1.x + v2.x + v3.x;
            ay += v0.y + v1.y + v2.y + v3.y;
        }
        for (; p < cnt; p++) {
            int s = __shfl(idx, p);
            float2 v = *(const float2*)(tbl + (size_t)s * C + c2);
            ax += v.x; ay += v.y;
        }
    }
    if (SELF) {
        float2 h = *(const float2*)(tbl + (size_t)i * C + c2);
        ax += h.x; ay += h.y;
    }
    const float sc = scale[i];
    ax *= sc; ay *= sc;
    if (BIASRELU) {
        float2 bb = *(const float2*)(bias + c2);
        ax = fmaxf(ax + bb.x, 0.f);
        ay = fmaxf(ay + bb.y, 0.f);
    }
    float2 r; r.x = ax; r.y = ay;
    *(float2*)(out + (size_t)i * C + c2) = r;
}

// ---------------- host ----------------

extern "C" void kernel_launch(void* const* d_in, const int* in_sizes, int n_in,
                              void* d_out, int out_size, void* d_ws, size_t ws_size,
                              hipStream_t stream) {
    const float* x   = (const float*)d_in[0];
    const float* W_g = (const float*)d_in[1];
    const float* b_g = (const float*)d_in[2];
    const float* W_l = (const float*)d_in[3];
    const float* b_l = (const float*)d_in[4];
    const float* W_r = (const float*)d_in[5];
    const int*   ei  = (const int*)d_in[6];

    const int N = in_sizes[0] / C;       // 102400
    const int E = in_sizes[6] / 2;       // 1638400

    // workspace carve (~61.2 MB)
    char* ws = (char*)d_ws;
    float* hbuf = (float*)ws;                               // N*C f32 (h / mean)
    int*   csr  = (int*)(ws + (size_t)N * C * 4);           // E ints
    int*   deg  = csr + E;                                  // N
    int*   fill = deg + N;                                  // N
    int*   offs = fill + N;                                 // N+1 (+pad)
    float* dinv = (float*)(offs + N + 4);                   // N
    float* cinv = dinv + N;                                 // N
    int*   bsum = (int*)(cinv + N);                         // 128

    float* out0 = (float*)d_out;                            // layer outputs, N*C each
    const size_t NC = (size_t)N * C;
    const int nb = (N + 1023) / 1024;                       // 100 scan blocks

    hipMemsetAsync(deg, 0, (size_t)N * 4, stream);
    deg_kernel<<<(E + 255) / 256, 256, 0, stream>>>(ei, deg, E);
    scan_partial<<<nb, 256, 0, stream>>>(deg, bsum, N);
    scan_mid<<<1, 128, 0, stream>>>(bsum, offs, nb, N);
    scan_final<<<nb, 1024, 0, stream>>>(deg, bsum, offs, fill, dinv, cinv, N);
    csr_fill<<<(E + 255) / 256, 256, 0, stream>>>(ei, fill, csr, E);

    // ---- GCN layer -> out slot 0 (h pre-scaled by dinv in GEMM epilogue)
    gemm_single<<<N / 64, THREADS_GEMM, 0, stream>>>(x, W_g, dinv, hbuf);
    agg_kernel<1, 1><<<(N + 3) / 4, 256, 0, stream>>>(hbuf, csr, offs, dinv, b_g, out0, N);

    // ---- 3 SAGE layers -> out slots 1..3
    for (int l = 0; l < 3; l++) {
        const float* xin = out0 + (size_t)l * NC;
        float* yout      = out0 + (size_t)(l + 1) * NC;
        agg_kernel<0, 0><<<(N + 3) / 4, 256, 0, stream>>>(xin, csr, offs, cinv,
                                                          nullptr, hbuf, N);
        gemm_fused<<<dim3(N / 128, 2), THREADS_GEMM, 0, stream>>>(
            hbuf, xin, W_l + (size_t)l * C * C, b_l + (size_t)l * C,
            W_r + (size_t)l * C * C, yout);
    }
}

// Round 4
// 846.422 us; speedup vs baseline: 1.9707x; 1.4493x over previous
//
#include <hip/hip_runtime.h>

#define C 128          // channels
typedef __attribute__((ext_vector_type(8))) short bf16x8;
typedef __attribute__((ext_vector_type(4))) float f32x4;

// ---------------- graph structure build ----------------

__global__ void deg_kernel(const int* __restrict__ ei, int* __restrict__ deg, int E) {
    int e = blockIdx.x * blockDim.x + threadIdx.x;
    if (e < E) atomicAdd(&deg[ei[E + e]], 1);   // dst = ei[E+e]
}

__global__ __launch_bounds__(256) void scan_partial(const int* __restrict__ deg,
                                                    int* __restrict__ bsum, int n) {
    __shared__ int red[4];
    const int base = blockIdx.x * 1024 + threadIdx.x * 4;
    int s = 0;
#pragma unroll
    for (int j = 0; j < 4; j++) { int i = base + j; if (i < n) s += deg[i]; }
    for (int off = 32; off > 0; off >>= 1) s += __shfl_down(s, off);
    if ((threadIdx.x & 63) == 0) red[threadIdx.x >> 6] = s;
    __syncthreads();
    if (threadIdx.x == 0) bsum[blockIdx.x] = red[0] + red[1] + red[2] + red[3];
}

__global__ __launch_bounds__(128) void scan_mid(int* __restrict__ bsum,
                                                int* __restrict__ offs, int nb, int n) {
    __shared__ int sh[128];
    const int t = threadIdx.x;
    const int v = (t < nb) ? bsum[t] : 0;
    sh[t] = v;
    __syncthreads();
    for (int off = 1; off < 128; off <<= 1) {
        int add = (t >= off) ? sh[t - off] : 0;
        __syncthreads();
        sh[t] += add;
        __syncthreads();
    }
    if (t < nb) bsum[t] = sh[t] - v;      // exclusive base for block t
    if (t == nb - 1) offs[n] = sh[t];     // total edge count
}

__global__ __launch_bounds__(1024) void scan_final(const int* __restrict__ deg,
        const int* __restrict__ bsum, int* __restrict__ offs, int* __restrict__ fill,
        float* __restrict__ dinv, float* __restrict__ cinv, int n) {
    __shared__ int sh[1024];
    const int t = threadIdx.x;
    const int gi = blockIdx.x * 1024 + t;
    const int d = (gi < n) ? deg[gi] : 0;
    sh[t] = d;
    __syncthreads();
    for (int off = 1; off < 1024; off <<= 1) {
        int add = (t >= off) ? sh[t - off] : 0;
        __syncthreads();
        sh[t] += add;
        __syncthreads();
    }
    if (gi < n) {
        const int excl = bsum[blockIdx.x] + sh[t] - d;
        offs[gi] = excl;
        fill[gi] = excl;
        dinv[gi] = rsqrtf((float)(d + 1));       // GCN: self-loop counted
        cinv[gi] = 1.0f / (float)max(d, 1);      // SAGE mean divisor
    }
}

__global__ void csr_fill(const int* __restrict__ ei, int* __restrict__ fill,
                         int* __restrict__ csr, int E) {
    int e = blockIdx.x * blockDim.x + threadIdx.x;
    if (e < E) {
        int d = ei[E + e];
        int p = atomicAdd(&fill[d], 1);
        csr[p] = ei[e];                          // src
    }
}

// ---------------- weight split precompute (hi/lo bf16, chunk-major) ----------------
// layout: [chunk][split][ch 128][k64 64] ushort; fused stacks K=256: k<128 Wl, k>=128 Wr
// sizes: GCN = 2 chunks * 16384 = 32768 ushorts; fused = 3 layers * 4 chunks * 16384
//        = 196608 ushorts, per-layer stride 65536.

__device__ __forceinline__ void split_bf16(float w, unsigned short& hb, unsigned short& lb) {
    unsigned u = __float_as_uint(w);
    hb = (unsigned short)(u >> 16);                       // truncation
    float hf = __uint_as_float(u & 0xffff0000u);
    lb = (unsigned short)(__float_as_uint(w - hf) >> 16); // residual, truncated
}

__global__ __launch_bounds__(256) void wprep_gcn(const float* __restrict__ Wg,
                                                 unsigned short* __restrict__ dst) {
    int idx = blockIdx.x * 256 + threadIdx.x;   // [2 chunks][128 ch][64 k64] = 16384
    if (idx >= 2 * 128 * 64) return;
    int k64 = idx & 63, ch = (idx >> 6) & 127, chunk = idx >> 13;
    int k = chunk * 64 + k64;
    unsigned short hb, lb;
    split_bf16(Wg[(size_t)k * 128 + ch], hb, lb);
    size_t base = ((size_t)chunk * 2) * 8192 + ch * 64 + k64;
    dst[base] = hb;
    dst[base + 8192] = lb;
}

__global__ __launch_bounds__(256) void wprep_fused(const float* __restrict__ Wl,
        const float* __restrict__ Wr, unsigned short* __restrict__ dst) {
    int idx = blockIdx.x * 256 + threadIdx.x;   // [3][4 chunks][128][64] = 98304
    if (idx >= 3 * 4 * 128 * 64) return;
    int k64 = idx & 63, ch = (idx >> 6) & 127, chunk = (idx >> 13) & 3, layer = idx >> 15;
    int k = chunk * 64 + k64;
    float w = (k < 128) ? Wl[((size_t)layer * 128 + k) * 128 + ch]
                        : Wr[((size_t)layer * 128 + (k - 128)) * 128 + ch];
    unsigned short hb, lb;
    split_bf16(w, hb, lb);
    size_t base = (((size_t)layer * 4 + chunk) * 2) * 8192 + ch * 64 + k64;
    dst[base] = hb;
    dst[base + 8192] = lb;
}

// ---------------- MFMA GEMM (split-3 bf16: xh*wh + xh*wl + xl*wh) ----------------
// Block: 256 thr (4 waves), 64 rows x 128 ch. Wave w owns rows [w*16, w*16+16).
// A loaded direct from global f32 (row read once), split to hi/lo bf16 in regs.
// B staged per 64-k chunk in LDS (32 KB), XOR-swizzled 16B units (2-way max).
// FUSED=1: A=[m|x] K=256, out=relu(acc+bias). FUSED=0: A=x K=128, out=acc*scale[row].
template<int FUSED>
__global__ __launch_bounds__(256) void gemm_mfma(
        const float* __restrict__ A0, const float* __restrict__ A1,
        const unsigned short* __restrict__ Wp, const float* __restrict__ bias,
        float* __restrict__ out) {
    const int NCHUNK = FUSED ? 4 : 2;
    __shared__ unsigned short Bs[2][128][64];   // 32 KB: [split][ch][k64]
    const int t = threadIdx.x;
    const int lane = t & 63;
    const int wv = t >> 6;
    const int rowbase = blockIdx.x * 64 + wv * 16;
    const int arow = rowbase + (lane & 15);
    const int kq = lane >> 4;                   // 0..3
    const int srow = t & 127, ssplit = t >> 7;  // staging: one (split,ch) row per thread

    f32x4 acc[8];
#pragma unroll
    for (int f = 0; f < 8; f++) acc[f] = (f32x4){0.f, 0.f, 0.f, 0.f};

    for (int c = 0; c < NCHUNK; c++) {
        __syncthreads();                        // prior reads of Bs complete
        {   // stage 32 KB: thread t copies its 64-bf16 row, swizzling 16B units
            const unsigned short* src = Wp + (size_t)c * 16384 + t * 64;
            unsigned short* drow = &Bs[ssplit][srow][0];
#pragma unroll
            for (int u = 0; u < 8; u++)
                ((uint4*)drow)[u ^ (srow & 7)] = ((const uint4*)src)[u];
        }
        // A fragments for this chunk (global f32 -> hi/lo bf16)
        bf16x8 Ah[2], Al[2];
#pragma unroll
        for (int j = 0; j < 2; j++) {
            const int kb = c * 64 + j * 32;
            const float* base;
            if (FUSED)
                base = (kb < 128) ? (A0 + (size_t)arow * C + kb)
                                  : (A1 + (size_t)arow * C + (kb - 128));
            else
                base = A0 + (size_t)arow * C + kb;
            float4 x0 = ((const float4*)base)[kq * 2];
            float4 x1 = ((const float4*)base)[kq * 2 + 1];
            float xv[8] = {x0.x, x0.y, x0.z, x0.w, x1.x, x1.y, x1.z, x1.w};
#pragma unroll
            for (int q = 0; q < 8; q++) {
                unsigned u = __float_as_uint(xv[q]);
                Ah[j][q] = (short)(u >> 16);
                float hf = __uint_as_float(u & 0xffff0000u);
                Al[j][q] = (short)(__float_as_uint(xv[q] - hf) >> 16);
            }
        }
        __syncthreads();                        // Bs staged
#pragma unroll
        for (int j = 0; j < 2; j++) {
#pragma unroll
            for (int f = 0; f < 8; f++) {
                const int chh = f * 16 + (lane & 15);
                const int uu = (j * 4 + kq) ^ (lane & 7);
                bf16x8 bh = *(const bf16x8*)&Bs[0][chh][uu * 8];
                bf16x8 bl = *(const bf16x8*)&Bs[1][chh][uu * 8];
                acc[f] = __builtin_amdgcn_mfma_f32_16x16x32_bf16(Ah[j], bh, acc[f], 0, 0, 0);
                acc[f] = __builtin_amdgcn_mfma_f32_16x16x32_bf16(Al[j], bh, acc[f], 0, 0, 0);
                acc[f] = __builtin_amdgcn_mfma_f32_16x16x32_bf16(Ah[j], bl, acc[f], 0, 0, 0);
            }
        }
    }
    // epilogue: C/D layout col=lane&15, row=(lane>>4)*4+j
    const int col = lane & 15;
    const int rq = lane >> 4;
    if (FUSED) {
#pragma unroll
        for (int f = 0; f < 8; f++) {
            const float b = bias[f * 16 + col];
#pragma unroll
            for (int j = 0; j < 4; j++) {
                const int r = rowbase + rq * 4 + j;
                out[(size_t)r * C + f * 16 + col] = fmaxf(acc[f][j] + b, 0.f);
            }
        }
    } else {
        float sc[4];
#pragma unroll
        for (int j = 0; j < 4; j++) sc[j] = bias[rowbase + rq * 4 + j];  // dinv
#pragma unroll
        for (int f = 0; f < 8; f++)
#pragma unroll
            for (int j = 0; j < 4; j++) {
                const int r = rowbase + rq * 4 + j;
                out[(size_t)r * C + f * 16 + col] = acc[f][j] * sc[j];
            }
    }
}

// ---------------- unified aggregation (gather via CSR) ----------------
template<int SELF, int BIASRELU>
__global__ __launch_bounds__(256) void agg_kernel(
        const float* __restrict__ tbl, const int* __restrict__ csr,
        const int* __restrict__ offs, const float* __restrict__ scale,
        const float* __restrict__ bias, float* __restrict__ out, int n) {
    const int lane = threadIdx.x & 63;
    const int i = (blockIdx.x << 2) + (threadIdx.x >> 6);
    if (i >= n) return;
    const int b = offs[i], e = offs[i + 1];
    const int c2 = lane * 2;
    float ax = 0.f, ay = 0.f;
    for (int base = b; base < e; base += 64) {
        const int cnt = min(64, e - base);
        int idx = (base + lane < e) ? csr[base + lane] : 0;
        int p = 0;
        for (; p + 4 <= cnt; p += 4) {
            int s0 = __shfl(idx, p);
            int s1 = __shfl(idx, p + 1);
            int s2 = __shfl(idx, p + 2);
            int s3 = __shfl(idx, p + 3);
            float2 v0 = *(const float2*)(tbl + (size_t)s0 * C + c2);
            float2 v1 = *(const float2*)(tbl + (size_t)s1 * C + c2);
            float2 v2 = *(const float2*)(tbl + (size_t)s2 * C + c2);
            float2 v3 = *(const float2*)(tbl + (size_t)s3 * C + c2);
            ax += v0.x + v1.x + v2.x + v3.x;
            ay += v0.y + v1.y + v2.y + v3.y;
        }
        for (; p < cnt; p++) {
            int s = __shfl(idx, p);
            float2 v = *(const float2*)(tbl + (size_t)s * C + c2);
            ax += v.x; ay += v.y;
        }
    }
    if (SELF) {
        float2 h = *(const float2*)(tbl + (size_t)i * C + c2);
        ax += h.x; ay += h.y;
    }
    const float sc = scale[i];
    ax *= sc; ay *= sc;
    if (BIASRELU) {
        float2 bb = *(const float2*)(bias + c2);
        ax = fmaxf(ax + bb.x, 0.f);
        ay = fmaxf(ay + bb.y, 0.f);
    }
    float2 r; r.x = ax; r.y = ay;
    *(float2*)(out + (size_t)i * C + c2) = r;
}

// ---------------- host ----------------

extern "C" void kernel_launch(void* const* d_in, const int* in_sizes, int n_in,
                              void* d_out, int out_size, void* d_ws, size_t ws_size,
                              hipStream_t stream) {
    const float* x   = (const float*)d_in[0];
    const float* W_g = (const float*)d_in[1];
    const float* b_g = (const float*)d_in[2];
    const float* W_l = (const float*)d_in[3];
    const float* b_l = (const float*)d_in[4];
    const float* W_r = (const float*)d_in[5];
    const int*   ei  = (const int*)d_in[6];

    const int N = in_sizes[0] / C;       // 102400
    const int E = in_sizes[6] / 2;       // 1638400

    // workspace carve (~61.5 MB)
    char* ws = (char*)d_ws;
    float* hbuf = (float*)ws;                               // N*C f32 (h / mean)
    int*   csr  = (int*)(ws + (size_t)N * C * 4);           // E ints
    int*   deg  = csr + E;                                  // N
    int*   fill = deg + N;                                  // N
    int*   offs = fill + N;                                 // N+1 (+pad)
    float* dinv = (float*)(offs + N + 4);                   // N
    float* cinv = dinv + N;                                 // N
    int*   bsum = (int*)(cinv + N);                         // 128
    unsigned short* wsWg = (unsigned short*)(bsum + 128);   // 2ch*2sp*8192 = 32768 ush
    unsigned short* wsWf = wsWg + 32768;                    // 3*4ch*2sp*8192 = 196608 ush

    float* out0 = (float*)d_out;                            // layer outputs, N*C each
    const size_t NC = (size_t)N * C;
    const int nb = (N + 1023) / 1024;                       // 100 scan blocks

    hipMemsetAsync(deg, 0, (size_t)N * 4, stream);
    deg_kernel<<<(E + 255) / 256, 256, 0, stream>>>(ei, deg, E);
    scan_partial<<<nb, 256, 0, stream>>>(deg, bsum, N);
    scan_mid<<<1, 128, 0, stream>>>(bsum, offs, nb, N);
    scan_final<<<nb, 1024, 0, stream>>>(deg, bsum, offs, fill, dinv, cinv, N);
    csr_fill<<<(E + 255) / 256, 256, 0, stream>>>(ei, fill, csr, E);
    wprep_gcn<<<64, 256, 0, stream>>>(W_g, wsWg);
    wprep_fused<<<384, 256, 0, stream>>>(W_l, W_r, wsWf);

    // ---- GCN layer -> out slot 0 (h pre-scaled by dinv in GEMM epilogue)
    gemm_mfma<0><<<N / 64, 256, 0, stream>>>(x, nullptr, wsWg, dinv, hbuf);
    agg_kernel<1, 1><<<(N + 3) / 4, 256, 0, stream>>>(hbuf, csr, offs, dinv, b_g, out0, N);

    // ---- 3 SAGE layers -> out slots 1..3
    for (int l = 0; l < 3; l++) {
        const float* xin = out0 + (size_t)l * NC;
        float* yout      = out0 + (size_t)(l + 1) * NC;
        agg_kernel<0, 0><<<(N + 3) / 4, 256, 0, stream>>>(xin, csr, offs, cinv,
                                                          nullptr, hbuf, N);
        gemm_mfma<1><<<N / 64, 256, 0, stream>>>(hbuf, xin, wsWf + (size_t)l * 65536,
                                                 b_l + (size_t)l * C, yout);
    }
}

// Round 5
// 576.321 us; speedup vs baseline: 2.8943x; 1.4687x over previous
//
#include <hip/hip_runtime.h>

#define C 128          // channels
typedef __attribute__((ext_vector_type(8))) short bf16x8;
typedef __attribute__((ext_vector_type(4))) float f32x4;

__device__ __forceinline__ unsigned short f2bf_rtn(float f) {
    unsigned u = __float_as_uint(f);
    return (unsigned short)((u + 0x7fff + ((u >> 16) & 1)) >> 16);
}

// ---------------- graph structure build ----------------

// degree count + per-edge rank within its dst bucket (removes atomics from fill)
__global__ void deg_rank_kernel(const int* __restrict__ ei, int* __restrict__ deg,
                                int* __restrict__ rank, int E) {
    int e = blockIdx.x * blockDim.x + threadIdx.x;
    if (e < E) rank[e] = atomicAdd(&deg[ei[E + e]], 1);   // dst = ei[E+e]
}

__global__ __launch_bounds__(256) void scan_partial(const int* __restrict__ deg,
                                                    int* __restrict__ bsum, int n) {
    __shared__ int red[4];
    const int base = blockIdx.x * 1024 + threadIdx.x * 4;
    int s = 0;
#pragma unroll
    for (int j = 0; j < 4; j++) { int i = base + j; if (i < n) s += deg[i]; }
    for (int off = 32; off > 0; off >>= 1) s += __shfl_down(s, off);
    if ((threadIdx.x & 63) == 0) red[threadIdx.x >> 6] = s;
    __syncthreads();
    if (threadIdx.x == 0) bsum[blockIdx.x] = red[0] + red[1] + red[2] + red[3];
}

__global__ __launch_bounds__(128) void scan_mid(int* __restrict__ bsum,
                                                int* __restrict__ offs, int nb, int n) {
    __shared__ int sh[128];
    const int t = threadIdx.x;
    const int v = (t < nb) ? bsum[t] : 0;
    sh[t] = v;
    __syncthreads();
    for (int off = 1; off < 128; off <<= 1) {
        int add = (t >= off) ? sh[t - off] : 0;
        __syncthreads();
        sh[t] += add;
        __syncthreads();
    }
    if (t < nb) bsum[t] = sh[t] - v;      // exclusive base for block t
    if (t == nb - 1) offs[n] = sh[t];     // total edge count
}

__global__ __launch_bounds__(1024) void scan_final(const int* __restrict__ deg,
        const int* __restrict__ bsum, int* __restrict__ offs,
        float* __restrict__ dinv, float* __restrict__ cinv, int n) {
    __shared__ int sh[1024];
    const int t = threadIdx.x;
    const int gi = blockIdx.x * 1024 + t;
    const int d = (gi < n) ? deg[gi] : 0;
    sh[t] = d;
    __syncthreads();
    for (int off = 1; off < 1024; off <<= 1) {
        int add = (t >= off) ? sh[t - off] : 0;
        __syncthreads();
        sh[t] += add;
        __syncthreads();
    }
    if (gi < n) {
        offs[gi] = bsum[blockIdx.x] + sh[t] - d;
        dinv[gi] = rsqrtf((float)(d + 1));       // GCN: self-loop counted
        cinv[gi] = 1.0f / (float)max(d, 1);      // SAGE mean divisor
    }
}

// atomic-free: position = offs[dst] + rank[e]
__global__ void csr_fill(const int* __restrict__ ei, const int* __restrict__ offs,
                         const int* __restrict__ rank, int* __restrict__ csr, int E) {
    int e = blockIdx.x * blockDim.x + threadIdx.x;
    if (e < E) csr[offs[ei[E + e]] + rank[e]] = ei[e];
}

// ---------------- weight split precompute (hi/lo bf16, chunk-major) ----------------
// layout: [chunk][split][ch 128][k64 64] ushort; fused stacks K=256: k<128 Wl, k>=128 Wr
// GCN = 2*16384 = 32768 ushorts; fused = 3 * 4 * 16384, per-layer stride 65536.

__device__ __forceinline__ void split_bf16(float w, unsigned short& hb, unsigned short& lb) {
    unsigned u = __float_as_uint(w);
    hb = (unsigned short)(u >> 16);                       // truncation
    float hf = __uint_as_float(u & 0xffff0000u);
    lb = (unsigned short)(__float_as_uint(w - hf) >> 16); // residual, truncated
}

__global__ __launch_bounds__(256) void wprep_gcn(const float* __restrict__ Wg,
                                                 unsigned short* __restrict__ dst) {
    int idx = blockIdx.x * 256 + threadIdx.x;   // [2 chunks][128 ch][64 k64] = 16384
    if (idx >= 2 * 128 * 64) return;
    int k64 = idx & 63, ch = (idx >> 6) & 127, chunk = idx >> 13;
    int k = chunk * 64 + k64;
    unsigned short hb, lb;
    split_bf16(Wg[(size_t)k * 128 + ch], hb, lb);
    size_t base = ((size_t)chunk * 2) * 8192 + ch * 64 + k64;
    dst[base] = hb;
    dst[base + 8192] = lb;
}

__global__ __launch_bounds__(256) void wprep_fused(const float* __restrict__ Wl,
        const float* __restrict__ Wr, unsigned short* __restrict__ dst) {
    int idx = blockIdx.x * 256 + threadIdx.x;   // [3][4 chunks][128][64] = 98304
    if (idx >= 3 * 4 * 128 * 64) return;
    int k64 = idx & 63, ch = (idx >> 6) & 127, chunk = (idx >> 13) & 3, layer = idx >> 15;
    int k = chunk * 64 + k64;
    float w = (k < 128) ? Wl[((size_t)layer * 128 + k) * 128 + ch]
                        : Wr[((size_t)layer * 128 + (k - 128)) * 128 + ch];
    unsigned short hb, lb;
    split_bf16(w, hb, lb);
    size_t base = (((size_t)layer * 4 + chunk) * 2) * 8192 + ch * 64 + k64;
    dst[base] = hb;
    dst[base + 8192] = lb;
}

// ---------------- MFMA GEMM ----------------
// Block: 256 thr (4 waves), 64 rows x 128 ch. Wave w owns rows [w*16, w*16+16).
// B staged per 64-k chunk in LDS (32 KB), XOR-swizzled 16B units.
// FUSED=0 (GCN): A = x f32 (K=128), split-3 (xh*wh + xl*wh + xh*wl);
//   epilogue: *dinv[row], write bf16 table only.
// FUSED=1 (SAGE): K=256 = [mean(bf16 direct, 2 mfma) | x(f32 split-3)];
//   epilogue: relu(acc+bias) -> f32 out (+ bf16 table if WBF).
template<int FUSED, int WBF>
__global__ __launch_bounds__(256) void gemm_mfma(
        const float* __restrict__ A0f, const unsigned short* __restrict__ Mbf,
        const unsigned short* __restrict__ Wp, const float* __restrict__ bias,
        float* __restrict__ outf, unsigned short* __restrict__ outbf) {
    const int NCHUNK = FUSED ? 4 : 2;
    __shared__ unsigned short Bs[2][128][64];   // 32 KB: [split][ch][k64]
    const int t = threadIdx.x;
    const int lane = t & 63;
    const int wv = t >> 6;
    const int rowbase = blockIdx.x * 64 + wv * 16;
    const int arow = rowbase + (lane & 15);
    const int kq = lane >> 4;                   // 0..3
    const int srow = t & 127, ssplit = t >> 7;

    f32x4 acc[8];
#pragma unroll
    for (int f = 0; f < 8; f++) acc[f] = (f32x4){0.f, 0.f, 0.f, 0.f};

#pragma unroll
    for (int c = 0; c < NCHUNK; c++) {
        __syncthreads();                        // prior reads of Bs complete
        {   // stage 32 KB: thread t copies its 64-bf16 row, swizzling 16B units
            const unsigned short* src = Wp + (size_t)c * 16384 + t * 64;
            unsigned short* drow = &Bs[ssplit][srow][0];
#pragma unroll
            for (int u = 0; u < 8; u++)
                ((uint4*)drow)[u ^ (srow & 7)] = ((const uint4*)src)[u];
        }
        const bool mside = (FUSED && c < 2);
        bf16x8 Ah[2], Al[2];
#pragma unroll
        for (int j = 0; j < 2; j++) {
            if (mside) {
                Ah[j] = *(const bf16x8*)(Mbf + (size_t)arow * C + c * 64 + j * 32 + kq * 8);
            } else {
                const int kb = (FUSED ? (c - 2) : c) * 64 + j * 32;
                const float* base = A0f + (size_t)arow * C + kb;
                float4 x0 = ((const float4*)base)[kq * 2];
                float4 x1 = ((const float4*)base)[kq * 2 + 1];
                float xv[8] = {x0.x, x0.y, x0.z, x0.w, x1.x, x1.y, x1.z, x1.w};
#pragma unroll
                for (int q = 0; q < 8; q++) {
                    unsigned u = __float_as_uint(xv[q]);
                    Ah[j][q] = (short)(u >> 16);
                    float hf = __uint_as_float(u & 0xffff0000u);
                    Al[j][q] = (short)(__float_as_uint(xv[q] - hf) >> 16);
                }
            }
        }
        __syncthreads();                        // Bs staged
#pragma unroll
        for (int j = 0; j < 2; j++) {
#pragma unroll
            for (int f = 0; f < 8; f++) {
                const int chh = f * 16 + (lane & 15);
                const int uu = (j * 4 + kq) ^ (lane & 7);
                bf16x8 bh = *(const bf16x8*)&Bs[0][chh][uu * 8];
                bf16x8 bl = *(const bf16x8*)&Bs[1][chh][uu * 8];
                acc[f] = __builtin_amdgcn_mfma_f32_16x16x32_bf16(Ah[j], bh, acc[f], 0, 0, 0);
                if (!mside)
                    acc[f] = __builtin_amdgcn_mfma_f32_16x16x32_bf16(Al[j], bh, acc[f], 0, 0, 0);
                acc[f] = __builtin_amdgcn_mfma_f32_16x16x32_bf16(Ah[j], bl, acc[f], 0, 0, 0);
            }
        }
    }
    // epilogue: C/D layout col=lane&15, row=(lane>>4)*4+j
    const int col = lane & 15;
    const int rq = lane >> 4;
    if (FUSED) {
#pragma unroll
        for (int f = 0; f < 8; f++) {
            const float b = bias[f * 16 + col];
#pragma unroll
            for (int j = 0; j < 4; j++) {
                const size_t o = (size_t)(rowbase + rq * 4 + j) * C + f * 16 + col;
                float v = fmaxf(acc[f][j] + b, 0.f);
                outf[o] = v;
                if (WBF) outbf[o] = f2bf_rtn(v);
            }
        }
    } else {
        float sc[4];
#pragma unroll
        for (int j = 0; j < 4; j++) sc[j] = bias[rowbase + rq * 4 + j];  // dinv
#pragma unroll
        for (int f = 0; f < 8; f++)
#pragma unroll
            for (int j = 0; j < 4; j++) {
                const size_t o = (size_t)(rowbase + rq * 4 + j) * C + f * 16 + col;
                outbf[o] = f2bf_rtn(acc[f][j] * sc[j]);
            }
    }
}

// ---------------- unified aggregation (bf16 gather via CSR) ----------------
// wave-per-node, 2 ch/lane (uint = ushort2), f32 accumulate.
template<int SELF, int BIASRELU, int WF, int WBF>
__global__ __launch_bounds__(256) void agg_kernel(
        const unsigned short* __restrict__ tbl, const int* __restrict__ csr,
        const int* __restrict__ offs, const float* __restrict__ scale,
        const float* __restrict__ bias, float* __restrict__ outf,
        unsigned short* __restrict__ outbf, int n) {
    const int lane = threadIdx.x & 63;
    const int i = (blockIdx.x << 2) + (threadIdx.x >> 6);
    if (i >= n) return;
    const int b = offs[i], e = offs[i + 1];
    const int c2 = lane * 2;
    float ax = 0.f, ay = 0.f;
    for (int base = b; base < e; base += 64) {
        const int cnt = min(64, e - base);
        int idx = (base + lane < e) ? csr[base + lane] : 0;
        int p = 0;
        for (; p + 4 <= cnt; p += 4) {
            int s0 = __shfl(idx, p);
            int s1 = __shfl(idx, p + 1);
            int s2 = __shfl(idx, p + 2);
            int s3 = __shfl(idx, p + 3);
            unsigned v0 = *(const unsigned*)(tbl + (size_t)s0 * C + c2);
            unsigned v1 = *(const unsigned*)(tbl + (size_t)s1 * C + c2);
            unsigned v2 = *(const unsigned*)(tbl + (size_t)s2 * C + c2);
            unsigned v3 = *(const unsigned*)(tbl + (size_t)s3 * C + c2);
            ax += __uint_as_float(v0 << 16) + __uint_as_float(v1 << 16)
                + __uint_as_float(v2 << 16) + __uint_as_float(v3 << 16);
            ay += __uint_as_float(v0 & 0xffff0000u) + __uint_as_float(v1 & 0xffff0000u)
                + __uint_as_float(v2 & 0xffff0000u) + __uint_as_float(v3 & 0xffff0000u);
        }
        for (; p < cnt; p++) {
            int s = __shfl(idx, p);
            unsigned v = *(const unsigned*)(tbl + (size_t)s * C + c2);
            ax += __uint_as_float(v << 16);
            ay += __uint_as_float(v & 0xffff0000u);
        }
    }
    if (SELF) {
        unsigned h = *(const unsigned*)(tbl + (size_t)i * C + c2);
        ax += __uint_as_float(h << 16);
        ay += __uint_as_float(h & 0xffff0000u);
    }
    const float sc = scale[i];
    ax *= sc; ay *= sc;
    if (BIASRELU) {
        float2 bb = *(const float2*)(bias + c2);
        ax = fmaxf(ax + bb.x, 0.f);
        ay = fmaxf(ay + bb.y, 0.f);
    }
    if (WF) {
        float2 r; r.x = ax; r.y = ay;
        *(float2*)(outf + (size_t)i * C + c2) = r;
    }
    if (WBF) {
        unsigned pk = (unsigned)f2bf_rtn(ax) | ((unsigned)f2bf_rtn(ay) << 16);
        *(unsigned*)(outbf + (size_t)i * C + c2) = pk;
    }
}

// ---------------- host ----------------

extern "C" void kernel_launch(void* const* d_in, const int* in_sizes, int n_in,
                              void* d_out, int out_size, void* d_ws, size_t ws_size,
                              hipStream_t stream) {
    const float* x   = (const float*)d_in[0];
    const float* W_g = (const float*)d_in[1];
    const float* b_g = (const float*)d_in[2];
    const float* W_l = (const float*)d_in[3];
    const float* b_l = (const float*)d_in[4];
    const float* W_r = (const float*)d_in[5];
    const int*   ei  = (const int*)d_in[6];

    const int N = in_sizes[0] / C;       // 102400
    const int E = in_sizes[6] / 2;       // 1638400
    const size_t NC = (size_t)N * C;

    // workspace carve (~87.4 MB)
    char* ws = (char*)d_ws;
    unsigned short* meanbf = (unsigned short*)ws;            // N*C bf16 (SAGE mean)
    unsigned short* tblA   = meanbf + NC;                    // N*C bf16 table
    unsigned short* tblB   = tblA + NC;                      // N*C bf16 table
    int* csr  = (int*)(tblB + NC);                           // E
    int* rank = (int*)tblA;   // overlay: rank dies at csr_fill, tblA born at gemm<0>
    int* deg  = csr + E;                                     // N
    int* offs = deg + N;                                     // N+1 (+pad)
    float* dinv = (float*)(offs + N + 4);                    // N
    float* cinv = dinv + N;                                  // N
    int* bsum = (int*)(cinv + N);                            // 128
    unsigned short* wsWg = (unsigned short*)(bsum + 128);    // 32768 ush
    unsigned short* wsWf = wsWg + 32768;                     // 196608 ush

    float* out0 = (float*)d_out;                             // layer outputs, N*C each
    const int nb = (N + 1023) / 1024;                        // 100 scan blocks

    hipMemsetAsync(deg, 0, (size_t)N * 4, stream);
    deg_rank_kernel<<<(E + 255) / 256, 256, 0, stream>>>(ei, deg, rank, E);
    scan_partial<<<nb, 256, 0, stream>>>(deg, bsum, N);
    scan_mid<<<1, 128, 0, stream>>>(bsum, offs, nb, N);
    scan_final<<<nb, 1024, 0, stream>>>(deg, bsum, offs, dinv, cinv, N);
    csr_fill<<<(E + 255) / 256, 256, 0, stream>>>(ei, offs, rank, csr, E);
    wprep_gcn<<<64, 256, 0, stream>>>(W_g, wsWg);
    wprep_fused<<<384, 256, 0, stream>>>(W_l, W_r, wsWf);

    // ---- GCN layer: h*dinv -> tblA (bf16); agg -> out slot 0 (f32) + tblB (bf16)
    gemm_mfma<0, 1><<<N / 64, 256, 0, stream>>>(x, nullptr, wsWg, dinv, nullptr, tblA);
    agg_kernel<1, 1, 1, 1><<<(N + 3) / 4, 256, 0, stream>>>(tblA, csr, offs, dinv,
                                                            b_g, out0, tblB, N);

    // ---- 3 SAGE layers -> out slots 1..3; tables ping-pong tblB->tblA->tblB
    const unsigned short* tin[3] = {tblB, tblA, tblB};
    unsigned short* tout[3] = {tblA, tblB, nullptr};
    for (int l = 0; l < 3; l++) {
        const float* xin = out0 + (size_t)l * NC;
        float* yout      = out0 + (size_t)(l + 1) * NC;
        agg_kernel<0, 0, 0, 1><<<(N + 3) / 4, 256, 0, stream>>>(
            tin[l], csr, offs, cinv, nullptr, nullptr, meanbf, N);
        if (l < 2)
            gemm_mfma<1, 1><<<N / 64, 256, 0, stream>>>(xin, meanbf,
                wsWf + (size_t)l * 65536, b_l + (size_t)l * C, yout, tout[l]);
        else
            gemm_mfma<1, 0><<<N / 64, 256, 0, stream>>>(xin, meanbf,
                wsWf + (size_t)l * 65536, b_l + (size_t)l * C, yout, nullptr);
    }
}